// Round 2
// baseline (3228.638 us; speedup 1.0000x reference)
//
#include <hip/hip_runtime.h>
#include <math.h>

// Problem constants: B=16, L=512, D=1024, H=4, hd=256, BL = B*L = 8192.

// ---------------------------------------------------------------------------
// LayerNorm over rows of 1024 floats. g/b optional (nullptr => parameter-free).
// One block (256 threads) per row; each thread owns 4 consecutive floats.
// ---------------------------------------------------------------------------
__global__ __launch_bounds__(256)
void ln_kernel(const float* __restrict__ x, const float* __restrict__ g,
               const float* __restrict__ b, float* __restrict__ y) {
    const size_t row = blockIdx.x;
    const float* xr = x + row * 1024;
    float* yr = y + row * 1024;
    const int t = threadIdx.x;

    float4 v = *(const float4*)(xr + t * 4);
    float s  = v.x + v.y + v.z + v.w;
    float ss = v.x * v.x + v.y * v.y + v.z * v.z + v.w * v.w;

#pragma unroll
    for (int off = 32; off; off >>= 1) {
        s  += __shfl_xor(s, off);
        ss += __shfl_xor(ss, off);
    }
    __shared__ float red[8];
    const int wave = t >> 6, lane = t & 63;
    if (lane == 0) { red[wave] = s; red[4 + wave] = ss; }
    __syncthreads();
    s  = red[0] + red[1] + red[2] + red[3];
    ss = red[4] + red[5] + red[6] + red[7];

    const float mu   = s * (1.0f / 1024.0f);
    const float var  = ss * (1.0f / 1024.0f) - mu * mu;
    const float rstd = rsqrtf(var + 1e-5f);

    float4 o;
    o.x = (v.x - mu) * rstd;
    o.y = (v.y - mu) * rstd;
    o.z = (v.z - mu) * rstd;
    o.w = (v.w - mu) * rstd;
    if (g != nullptr) {
        float4 gv = *(const float4*)(g + t * 4);
        float4 bv = *(const float4*)(b + t * 4);
        o.x = o.x * gv.x + bv.x;
        o.y = o.y * gv.y + bv.y;
        o.z = o.z * gv.z + bv.z;
        o.w = o.w * gv.w + bv.w;
    }
    *(float4*)(yr + t * 4) = o;
}

// ---------------------------------------------------------------------------
// FP32 tiled GEMM: C[M,N] = A[M,K] @ W[K,N] (+bias) (+R) (ReLU) (+=C if ACCUM).
// W has row stride ldw (>= N) so column-slices of a wider matrix work.
// BM=BN=128, BK=8, 256 threads, 8x8 per thread in 2x2 quadrants of 4.
// M,N divisible by 128; K divisible by 8 (true for all uses here).
// ---------------------------------------------------------------------------
template<bool RELU, bool RES, bool ACCUM>
__global__ __launch_bounds__(256)
void gemm_kernel(const float* __restrict__ A, const float* __restrict__ W,
                 const float* __restrict__ bias, const float* __restrict__ R,
                 float* __restrict__ C, int M, int N, int K, int ldw) {
    __shared__ float As[8][128];   // [k][m]
    __shared__ float Ws[8][128];   // [k][n]

    const int tid  = threadIdx.x;
    const int row0 = blockIdx.y * 128;
    const int col0 = blockIdx.x * 128;
    const int tx = tid & 15;       // n dimension (16)
    const int ty = tid >> 4;       // m dimension (16)

    // A tile load: thread -> A[row0 + tid/2][(tid&1)*4 .. +3]  (128x8 = 1024 f)
    const int arow = tid >> 1;
    const int acol = (tid & 1) * 4;
    // W tile load: thread -> W[tid/32][col0 + (tid&31)*4 .. +3] (8x128 = 1024 f)
    const int wrow = tid >> 5;
    const int wcol = (tid & 31) * 4;

    const float* Aptr = A + (size_t)(row0 + arow) * K + acol;
    const float* Wptr = W + (size_t)wrow * ldw + col0 + wcol;

    float acc[8][8];
#pragma unroll
    for (int i = 0; i < 8; ++i)
#pragma unroll
        for (int j = 0; j < 8; ++j) acc[i][j] = 0.0f;

    for (int k0 = 0; k0 < K; k0 += 8) {
        const float4 av = *(const float4*)(Aptr + k0);
        const float4 wv = *(const float4*)(Wptr + (size_t)k0 * ldw);
        __syncthreads();   // previous iteration's reads done before overwrite
        As[acol + 0][arow] = av.x;
        As[acol + 1][arow] = av.y;
        As[acol + 2][arow] = av.z;
        As[acol + 3][arow] = av.w;
        *(float4*)&Ws[wrow][wcol] = wv;
        __syncthreads();

#pragma unroll
        for (int kk = 0; kk < 8; ++kk) {
            const float4 a0 = *(const float4*)&As[kk][ty * 4];
            const float4 a1 = *(const float4*)&As[kk][64 + ty * 4];
            const float4 b0 = *(const float4*)&Ws[kk][tx * 4];
            const float4 b1 = *(const float4*)&Ws[kk][64 + tx * 4];
            const float a[8] = {a0.x, a0.y, a0.z, a0.w, a1.x, a1.y, a1.z, a1.w};
            const float bb[8] = {b0.x, b0.y, b0.z, b0.w, b1.x, b1.y, b1.z, b1.w};
#pragma unroll
            for (int i = 0; i < 8; ++i)
#pragma unroll
                for (int j = 0; j < 8; ++j)
                    acc[i][j] = fmaf(a[i], bb[j], acc[i][j]);
        }
    }

    // Epilogue: rows = row0 + {ty*4+i, 64+ty*4+i}; cols = col0 + {tx*4+j, 64+tx*4+j}
    const int c0 = col0 + tx * 4;
    const int c1 = col0 + 64 + tx * 4;
    float4 bv0 = {0.f, 0.f, 0.f, 0.f}, bv1 = {0.f, 0.f, 0.f, 0.f};
    if (bias != nullptr) {
        bv0 = *(const float4*)(bias + c0);
        bv1 = *(const float4*)(bias + c1);
    }

#pragma unroll
    for (int i = 0; i < 8; ++i) {
        const int r = row0 + ((i < 4) ? (ty * 4 + i) : (64 + ty * 4 + (i - 4)));
        const size_t base = (size_t)r * N;
        float4 o0, o1;
        o0.x = acc[i][0] + bv0.x; o0.y = acc[i][1] + bv0.y;
        o0.z = acc[i][2] + bv0.z; o0.w = acc[i][3] + bv0.w;
        o1.x = acc[i][4] + bv1.x; o1.y = acc[i][5] + bv1.y;
        o1.z = acc[i][6] + bv1.z; o1.w = acc[i][7] + bv1.w;
        if (RES) {
            const float4 r0 = *(const float4*)(R + base + c0);
            const float4 r1 = *(const float4*)(R + base + c1);
            o0.x += r0.x; o0.y += r0.y; o0.z += r0.z; o0.w += r0.w;
            o1.x += r1.x; o1.y += r1.y; o1.z += r1.z; o1.w += r1.w;
        }
        if (RELU) {
            o0.x = fmaxf(o0.x, 0.0f); o0.y = fmaxf(o0.y, 0.0f);
            o0.z = fmaxf(o0.z, 0.0f); o0.w = fmaxf(o0.w, 0.0f);
            o1.x = fmaxf(o1.x, 0.0f); o1.y = fmaxf(o1.y, 0.0f);
            o1.z = fmaxf(o1.z, 0.0f); o1.w = fmaxf(o1.w, 0.0f);
        }
        if (ACCUM) {
            const float4 p0 = *(const float4*)(C + base + c0);
            const float4 p1 = *(const float4*)(C + base + c1);
            o0.x += p0.x; o0.y += p0.y; o0.z += p0.z; o0.w += p0.w;
            o1.x += p1.x; o1.y += p1.y; o1.z += p1.z; o1.w += p1.w;
        }
        *(float4*)(C + base + c0) = o0;
        *(float4*)(C + base + c1) = o1;
    }
}

// ---------------------------------------------------------------------------
// Fused attention: per block, one (b, h, 16-query-row tile).
//   scores = Q Kt / 16 ; row-0: (s + cbias[m]) * sharp ; softmax ; out = P V.
// Head 0's probabilities are written straight into d_out's attn region.
// q/k/v layout: [B, L, H, hd] flat (== GEMM output [BL, D] with col = h*256+d).
// ---------------------------------------------------------------------------
__global__ __launch_bounds__(256)
void attn_kernel(const float* __restrict__ q, const float* __restrict__ k,
                 const float* __restrict__ v, const float* __restrict__ cbias,
                 const float* __restrict__ sharp, float* __restrict__ attn_out,
                 float* __restrict__ out_attn) {
    __shared__ float qs[16][256];   // 16 KB
    __shared__ float ps[16][512];   // 32 KB

    const int blk  = blockIdx.x;          // 2048 = 16b * 4h * 32qt
    const int b    = blk >> 7;
    const int h    = (blk >> 5) & 3;
    const int qt   = blk & 31;
    const int row0 = qt * 16;
    const int t    = threadIdx.x;

    // ---- load Q tile (16 x 256) ----
    {
        const float* qbase = q + (((size_t)b * 512 + row0) * 4 + h) * 256;
#pragma unroll
        for (int it = 0; it < 4; ++it) {
            const int flat = t * 4 + it * 1024;
            const int r = flat >> 8, d = flat & 255;
            *(float4*)&qs[r][d] = *(const float4*)(qbase + (size_t)r * 1024 + d);
        }
    }
    __syncthreads();

    // ---- scores: thread owns key columns m=t and m=t+256 ----
    {
        const float* kb0 = k + (((size_t)b * 512 + t) * 4 + h) * 256;
        const float* kb1 = kb0 + (size_t)256 * 1024;
        float acc0[16], acc1[16];
#pragma unroll
        for (int r = 0; r < 16; ++r) { acc0[r] = 0.0f; acc1[r] = 0.0f; }
        for (int d = 0; d < 256; d += 4) {
            const float4 k0 = *(const float4*)(kb0 + d);
            const float4 k1 = *(const float4*)(kb1 + d);
#pragma unroll
            for (int r = 0; r < 16; ++r) {
                const float4 qv = *(const float4*)&qs[r][d];
                acc0[r] += qv.x * k0.x + qv.y * k0.y + qv.z * k0.z + qv.w * k0.w;
                acc1[r] += qv.x * k1.x + qv.y * k1.y + qv.z * k1.z + qv.w * k1.w;
            }
        }
        const float sh = sharp[0];
#pragma unroll
        for (int r = 0; r < 16; ++r) {
            float s0 = acc0[r] * 0.0625f;
            float s1 = acc1[r] * 0.0625f;
            if (row0 + r == 0) {                 // global query position 0
                s0 = (s0 + cbias[t]) * sh;
                s1 = (s1 + cbias[t + 256]) * sh;
            }
            ps[r][t] = s0;
            ps[r][t + 256] = s1;
        }
    }
    __syncthreads();

    // ---- softmax: wave w handles rows w, w+4, w+8, w+12 ----
    {
        const int wave = t >> 6, lane = t & 63;
#pragma unroll
        for (int rr = 0; rr < 4; ++rr) {
            const int r = wave + rr * 4;
            float vals[8];
            float m = -1e30f;
#pragma unroll
            for (int j = 0; j < 8; ++j) {
                vals[j] = ps[r][lane + j * 64];
                m = fmaxf(m, vals[j]);
            }
#pragma unroll
            for (int off = 32; off; off >>= 1) m = fmaxf(m, __shfl_xor(m, off));
            float sum = 0.0f;
#pragma unroll
            for (int j = 0; j < 8; ++j) { vals[j] = expf(vals[j] - m); sum += vals[j]; }
#pragma unroll
            for (int off = 32; off; off >>= 1) sum += __shfl_xor(sum, off);
            const float inv = 1.0f / sum;
#pragma unroll
            for (int j = 0; j < 8; ++j) ps[r][lane + j * 64] = vals[j] * inv;
        }
    }
    __syncthreads();

    // ---- head-0 probabilities -> d_out attn region [B, L, L] ----
    if (h == 0) {
        float* ob = out_attn + ((size_t)b * 512 + row0) * 512;
#pragma unroll 4
        for (int it = 0; it < 32; ++it) {
            const int flat = t + it * 256;
            const int r = flat >> 9, m = flat & 511;
            ob[(size_t)r * 512 + m] = ps[r][m];
        }
    }

    // ---- PV: thread owns d = t for all 16 rows ----
    {
        float accp[16];
#pragma unroll
        for (int r = 0; r < 16; ++r) accp[r] = 0.0f;
        const float* vbp = v + (((size_t)b * 512) * 4 + h) * 256 + t;
        for (int m = 0; m < 512; m += 4) {
            const float v0 = vbp[(size_t)(m + 0) * 1024];
            const float v1 = vbp[(size_t)(m + 1) * 1024];
            const float v2 = vbp[(size_t)(m + 2) * 1024];
            const float v3 = vbp[(size_t)(m + 3) * 1024];
#pragma unroll
            for (int r = 0; r < 16; ++r) {
                const float4 p = *(const float4*)&ps[r][m];
                accp[r] += p.x * v0 + p.y * v1 + p.z * v2 + p.w * v3;
            }
        }
        float* ob = attn_out + (((size_t)b * 512 + row0) * 4 + h) * 256 + t;
#pragma unroll
        for (int r = 0; r < 16; ++r) ob[(size_t)r * 1024] = accp[r];
    }
}

__global__ void copy_kernel(const float* __restrict__ in, float* __restrict__ out, int n) {
    const int i = blockIdx.x * blockDim.x + threadIdx.x;
    if (i < n) out[i] = in[i];
}

// ---------------------------------------------------------------------------
// Orchestration. Peak workspace: 4 units x 32 MB = 128 MiB.
//   u0: s_ln            -> attn_out (after QKV)
//   u1: q               -> hbuf (LN2 out, after attention)
//   u2: k               -> hidden_half (part 0)
//   u3: v               -> hidden_half (part 1)
// s1 (post-attn residual) lives directly in d_out's s region (in-place
// residual accumulate by the MLP-down GEMMs: one thread owns each element,
// read-before-write, so it is race-free).
// d_out: [ s (8,388,608) | z (4,096) | attn_head0 (4,194,304) ] floats.
// ---------------------------------------------------------------------------
extern "C" void kernel_launch(void* const* d_in, const int* in_sizes, int n_in,
                              void* d_out, int out_size, void* d_ws, size_t ws_size,
                              hipStream_t stream) {
    (void)in_sizes; (void)n_in; (void)out_size; (void)ws_size;

    const float* s     = (const float*)d_in[0];
    const float* z     = (const float*)d_in[1];
    const float* wq    = (const float*)d_in[2];
    const float* bq    = (const float*)d_in[3];
    const float* wk    = (const float*)d_in[4];
    const float* bk    = (const float*)d_in[5];
    const float* wv    = (const float*)d_in[6];
    const float* bv    = (const float*)d_in[7];
    const float* wo    = (const float*)d_in[8];
    const float* bo    = (const float*)d_in[9];
    const float* cbias = (const float*)d_in[10];
    const float* sharp = (const float*)d_in[11];
    const float* ln_g  = (const float*)d_in[12];
    const float* ln_b  = (const float*)d_in[13];
    const float* w1    = (const float*)d_in[14];
    const float* b1    = (const float*)d_in[15];
    const float* w2    = (const float*)d_in[16];
    const float* b2    = (const float*)d_in[17];

    float* ws = (float*)d_ws;
    const size_t U = (size_t)8192 * 1024;
    float* u0 = ws + 0 * U;    // sln -> attn_out
    float* u1 = ws + 1 * U;    // q   -> hbuf
    float* u2 = ws + 2 * U;    // k   -> hidden_half (spans u2..u3)
    float* u3 = ws + 3 * U;    // v

    float* out_s    = (float*)d_out;            // also s1 (post-attn residual)
    float* out_z    = out_s + U;
    float* out_attn = out_z + 16 * 256;

    // 1. LN1 (parameter-free): sln = LN(s)
    ln_kernel<<<8192, 256, 0, stream>>>(s, nullptr, nullptr, u0);

    // 2. QKV projections
    const dim3 gq(1024 / 128, 8192 / 128);
    gemm_kernel<false, false, false><<<gq, 256, 0, stream>>>(u0, wq, bq, nullptr, u1, 8192, 1024, 1024, 1024);
    gemm_kernel<false, false, false><<<gq, 256, 0, stream>>>(u0, wk, bk, nullptr, u2, 8192, 1024, 1024, 1024);
    gemm_kernel<false, false, false><<<gq, 256, 0, stream>>>(u0, wv, bv, nullptr, u3, 8192, 1024, 1024, 1024);

    // 3. Attention: attn_out -> u0 (sln dead), head-0 probs -> d_out
    attn_kernel<<<2048, 256, 0, stream>>>(u1, u2, u3, cbias, sharp, u0, out_attn);

    // 4. Output projection + residual: out_s = attn_out @ wo + bo + s
    gemm_kernel<false, true, false><<<gq, 256, 0, stream>>>(u0, wo, bo, s, out_s, 8192, 1024, 1024, 1024);

    // 5. LN2 (with gamma/beta): hbuf = LN(out_s) -> u1 (q dead)
    ln_kernel<<<8192, 256, 0, stream>>>(out_s, ln_g, ln_b, u1);

    // 6. MLP in two K-halves of 2048 (hidden_half reuses u2..u3, 64 MB):
    //    hidden = relu(hbuf @ w1[:, j*2048 : (j+1)*2048] + b1[j*2048:...])
    //    out_s += hidden @ w2[j*2048:(j+1)*2048, :]   (+ b2 on pass 0)
    const dim3 gup(2048 / 128, 8192 / 128);
    const dim3 gdn(1024 / 128, 8192 / 128);
    for (int j = 0; j < 2; ++j) {
        gemm_kernel<true, false, false><<<gup, 256, 0, stream>>>(
            u1, w1 + (size_t)j * 2048, b1 + (size_t)j * 2048, nullptr, u2,
            8192, 2048, 1024, 4096);
        gemm_kernel<false, false, true><<<gdn, 256, 0, stream>>>(
            u2, w2 + (size_t)j * 2048 * 1024, (j == 0) ? b2 : nullptr, nullptr, out_s,
            8192, 1024, 2048, 1024);
    }

    // 7. z passthrough
    copy_kernel<<<16, 256, 0, stream>>>(z, out_z, 4096);
}

// Round 4
// 2836.018 us; speedup vs baseline: 1.1384x; 1.1384x over previous
//
#include <hip/hip_runtime.h>
#include <math.h>

// Problem constants: B=16, L=512, D=1024, H=4, hd=256, BL = B*L = 8192.

typedef unsigned short u16;
typedef __attribute__((ext_vector_type(8))) short bf16x8;
typedef __attribute__((ext_vector_type(4))) float f32x4;

// Split fp32 into bf16 hi + bf16 lo (RNE both). x ~= hi + lo with ~2^-16 rel err.
__device__ inline void split2(float x, u16& h, u16& l) {
    union F { float f; unsigned int u; };
    F a; a.f = x;
    unsigned int hu = (a.u + 0x7FFFu + ((a.u >> 16) & 1u)) & 0xFFFF0000u;
    h = (u16)(hu >> 16);
    F hf; hf.u = hu;
    F r; r.f = x - hf.f;
    l = (u16)((r.u + 0x7FFFu + ((r.u >> 16) & 1u)) >> 16);
}

// ---------------------------------------------------------------------------
// LayerNorm over rows of 1024 floats -> bf16 hi/lo planes (GEMM A operand).
// ---------------------------------------------------------------------------
__global__ __launch_bounds__(256)
void ln_split_kernel(const float* __restrict__ x, const float* __restrict__ g,
                     const float* __restrict__ b, u16* __restrict__ yh,
                     u16* __restrict__ yl) {
    const size_t row = blockIdx.x;
    const float* xr = x + row * 1024;
    const int t = threadIdx.x;

    float4 v = *(const float4*)(xr + t * 4);
    float s  = v.x + v.y + v.z + v.w;
    float ss = v.x * v.x + v.y * v.y + v.z * v.z + v.w * v.w;

#pragma unroll
    for (int off = 32; off; off >>= 1) {
        s  += __shfl_xor(s, off);
        ss += __shfl_xor(ss, off);
    }
    __shared__ float red[8];
    const int wave = t >> 6, lane = t & 63;
    if (lane == 0) { red[wave] = s; red[4 + wave] = ss; }
    __syncthreads();
    s  = red[0] + red[1] + red[2] + red[3];
    ss = red[4] + red[5] + red[6] + red[7];

    const float mu   = s * (1.0f / 1024.0f);
    const float var  = ss * (1.0f / 1024.0f) - mu * mu;
    const float rstd = rsqrtf(var + 1e-5f);

    float o[4] = {(v.x - mu) * rstd, (v.y - mu) * rstd,
                  (v.z - mu) * rstd, (v.w - mu) * rstd};
    if (g != nullptr) {
        float4 gv = *(const float4*)(g + t * 4);
        float4 bv = *(const float4*)(b + t * 4);
        o[0] = o[0] * gv.x + bv.x; o[1] = o[1] * gv.y + bv.y;
        o[2] = o[2] * gv.z + bv.z; o[3] = o[3] * gv.w + bv.w;
    }
    ushort4 vh, vl;
    split2(o[0], vh.x, vl.x); split2(o[1], vh.y, vl.y);
    split2(o[2], vh.z, vl.z); split2(o[3], vh.w, vl.w);
    *(ushort4*)(yh + row * 1024 + t * 4) = vh;
    *(ushort4*)(yl + row * 1024 + t * 4) = vl;
}

// ---------------------------------------------------------------------------
// Weight prep: W[K][N] fp32 -> transposed bf16 planes Thi/Tlo [N][K].
// 64x64 tiles via LDS; grid (N/64, K/64), 256 threads.
// ---------------------------------------------------------------------------
__global__ __launch_bounds__(256)
void split_t_kernel(const float* __restrict__ W, u16* __restrict__ Thi,
                    u16* __restrict__ Tlo, int K, int N) {
    __shared__ float tile[64][65];
    const int bn = blockIdx.x, bk = blockIdx.y;
    const int t = threadIdx.x;
    const int col = t & 63, rquad = t >> 6;

#pragma unroll
    for (int rep = 0; rep < 16; ++rep) {
        const int row = rep * 4 + rquad;
        tile[row][col] = W[(size_t)(bk * 64 + row) * N + bn * 64 + col];
    }
    __syncthreads();
#pragma unroll
    for (int rep = 0; rep < 16; ++rep) {
        const int n = rep * 4 + rquad;
        const int k = col;
        u16 h, l;
        split2(tile[k][n], h, l);
        const size_t o = (size_t)(bn * 64 + n) * K + bk * 64 + k;
        Thi[o] = h; Tlo[o] = l;
    }
}

// ---------------------------------------------------------------------------
// Split-bf16 MFMA GEMM: C[M,N] = (Ah+Al)[M,K] @ (Bh+Bl)^T[N,K] (+bias)(+R)
// (ReLU)(+=C)(or split to Chi/Clo planes).
// A planes: [M][K] bf16 row-major (lda = K). B planes: [N][K] bf16 (ldb param).
// Tile 128x128xBK32. 4 waves, each 64x64 = 4x4 frags of 16x16x32.
// Per product: 3 MFMAs (hh, hl, lh) -> ~fp32 precision.
// ---------------------------------------------------------------------------
template<bool RELU, bool RES, bool ACCUM, bool SPLIT_OUT>
__global__ __launch_bounds__(256)
void mgemm(const u16* __restrict__ Ah, const u16* __restrict__ Al,
           const u16* __restrict__ Bh, const u16* __restrict__ Bl,
           const float* __restrict__ bias, const float* __restrict__ R,
           float* __restrict__ C, u16* __restrict__ Chi, u16* __restrict__ Clo,
           int M, int N, int K, int ldb) {
    // Rows padded to 40 ushorts (80 B, 16B-aligned) to spread banks.
    __shared__ u16 Ahs[128 * 40];
    __shared__ u16 Als[128 * 40];
    __shared__ u16 Bhs[128 * 40];
    __shared__ u16 Bls[128 * 40];

    const int tid  = threadIdx.x;
    const int lane = tid & 63;
    const int wid  = tid >> 6;
    const int wr = wid >> 1, wc = wid & 1;       // wave grid 2x2, 64x64 each
    const int fr = lane & 15, kb = lane >> 4;    // frag row / k-block
    const int row0 = blockIdx.y * 128, col0 = blockIdx.x * 128;

    // Staging: threads 0..127 stage A planes, 128..255 stage B planes.
    // Each thread: 4 rows (s2*32+rq), one 16B block (sb) per row, both planes.
    const int side = tid >> 7;
    const int su = tid & 127;
    const int rq = su >> 2, sb = su & 3;
    const u16* Ph = side ? Bh : Ah;
    const u16* Pl = side ? Bl : Al;
    const int brow = side ? col0 : row0;
    const int pst  = side ? ldb : K;
    u16* Lh = side ? Bhs : Ahs;
    u16* Ll = side ? Bls : Als;

    uint4 sh[4], sl[4];
#pragma unroll
    for (int s2 = 0; s2 < 4; ++s2) {
        const size_t off = (size_t)(brow + s2 * 32 + rq) * pst + sb * 8;
        sh[s2] = *(const uint4*)(Ph + off);
        sl[s2] = *(const uint4*)(Pl + off);
    }
#pragma unroll
    for (int s2 = 0; s2 < 4; ++s2) {
        const int r = s2 * 32 + rq;
        *(uint4*)&Lh[r * 40 + sb * 8] = sh[s2];
        *(uint4*)&Ll[r * 40 + sb * 8] = sl[s2];
    }

    f32x4 acc[4][4];
#pragma unroll
    for (int i = 0; i < 4; ++i)
#pragma unroll
        for (int j = 0; j < 4; ++j)
            acc[i][j] = (f32x4){0.f, 0.f, 0.f, 0.f};

    for (int ks = 0; ks < K; ks += 32) {
        __syncthreads();                     // tile ready
        if (ks + 32 < K) {                   // prefetch next tile to regs
#pragma unroll
            for (int s2 = 0; s2 < 4; ++s2) {
                const size_t off = (size_t)(brow + s2 * 32 + rq) * pst + (ks + 32) + sb * 8;
                sh[s2] = *(const uint4*)(Ph + off);
                sl[s2] = *(const uint4*)(Pl + off);
            }
        }
        bf16x8 fah[4], fal[4], fbh[4], fbl[4];
#pragma unroll
        for (int i = 0; i < 4; ++i) {
            const int ar = wr * 64 + i * 16 + fr;
            fah[i] = *(const bf16x8*)&Ahs[ar * 40 + kb * 8];
            fal[i] = *(const bf16x8*)&Als[ar * 40 + kb * 8];
            const int br = wc * 64 + i * 16 + fr;
            fbh[i] = *(const bf16x8*)&Bhs[br * 40 + kb * 8];
            fbl[i] = *(const bf16x8*)&Bls[br * 40 + kb * 8];
        }
#pragma unroll
        for (int mi = 0; mi < 4; ++mi)
#pragma unroll
            for (int nj = 0; nj < 4; ++nj) {
                acc[mi][nj] = __builtin_amdgcn_mfma_f32_16x16x32_bf16(fah[mi], fbh[nj], acc[mi][nj], 0, 0, 0);
                acc[mi][nj] = __builtin_amdgcn_mfma_f32_16x16x32_bf16(fah[mi], fbl[nj], acc[mi][nj], 0, 0, 0);
                acc[mi][nj] = __builtin_amdgcn_mfma_f32_16x16x32_bf16(fal[mi], fbh[nj], acc[mi][nj], 0, 0, 0);
            }
        __syncthreads();                     // reads done
        if (ks + 32 < K) {
#pragma unroll
            for (int s2 = 0; s2 < 4; ++s2) {
                const int r = s2 * 32 + rq;
                *(uint4*)&Lh[r * 40 + sb * 8] = sh[s2];
                *(uint4*)&Ll[r * 40 + sb * 8] = sl[s2];
            }
        }
    }

    // Epilogue. C/D frag mapping (m89/m91): col = lane&15, row = (lane>>4)*4+i.
#pragma unroll
    for (int mi = 0; mi < 4; ++mi)
#pragma unroll
        for (int nj = 0; nj < 4; ++nj) {
            const int gc = col0 + wc * 64 + nj * 16 + fr;
            const float bv = (bias != nullptr) ? bias[gc] : 0.0f;
#pragma unroll
            for (int i = 0; i < 4; ++i) {
                const int gr = row0 + wr * 64 + mi * 16 + kb * 4 + i;
                const size_t o = (size_t)gr * N + gc;
                float v2 = acc[mi][nj][i] + bv;
                if (RES)   v2 += R[o];
                if (RELU)  v2 = fmaxf(v2, 0.0f);
                if (ACCUM) v2 += C[o];
                if (SPLIT_OUT) {
                    u16 hh, ll; split2(v2, hh, ll);
                    Chi[o] = hh; Clo[o] = ll;
                } else {
                    C[o] = v2;
                }
            }
        }
}

// ---------------------------------------------------------------------------
// Fused attention (fp32, unchanged math): per block one (b, head, 16-q-rows).
// PV epilogue emits bf16 hi/lo planes (A operand of the Wo GEMM).
// ---------------------------------------------------------------------------
__global__ __launch_bounds__(256)
void attn_kernel(const float* __restrict__ q, const float* __restrict__ k,
                 const float* __restrict__ v, const float* __restrict__ cbias,
                 const float* __restrict__ sharp, u16* __restrict__ ao_hi,
                 u16* __restrict__ ao_lo, float* __restrict__ out_attn) {
    __shared__ float qs[16][256];   // 16 KB
    __shared__ float ps[16][512];   // 32 KB

    const int blk  = blockIdx.x;          // 2048 = 16b * 4h * 32qt
    const int b    = blk >> 7;
    const int h    = (blk >> 5) & 3;
    const int qt   = blk & 31;
    const int row0 = qt * 16;
    const int t    = threadIdx.x;

    // ---- load Q tile (16 x 256) ----
    {
        const float* qbase = q + (((size_t)b * 512 + row0) * 4 + h) * 256;
#pragma unroll
        for (int it = 0; it < 4; ++it) {
            const int flat = t * 4 + it * 1024;
            const int r = flat >> 8, d = flat & 255;
            *(float4*)&qs[r][d] = *(const float4*)(qbase + (size_t)r * 1024 + d);
        }
    }
    __syncthreads();

    // ---- scores: thread owns key columns m=t and m=t+256 ----
    {
        const float* kb0 = k + (((size_t)b * 512 + t) * 4 + h) * 256;
        const float* kb1 = kb0 + (size_t)256 * 1024;
        float acc0[16], acc1[16];
#pragma unroll
        for (int r = 0; r < 16; ++r) { acc0[r] = 0.0f; acc1[r] = 0.0f; }
        for (int d = 0; d < 256; d += 4) {
            const float4 k0 = *(const float4*)(kb0 + d);
            const float4 k1 = *(const float4*)(kb1 + d);
#pragma unroll
            for (int r = 0; r < 16; ++r) {
                const float4 qv = *(const float4*)&qs[r][d];
                acc0[r] += qv.x * k0.x + qv.y * k0.y + qv.z * k0.z + qv.w * k0.w;
                acc1[r] += qv.x * k1.x + qv.y * k1.y + qv.z * k1.z + qv.w * k1.w;
            }
        }
        const float sh = sharp[0];
#pragma unroll
        for (int r = 0; r < 16; ++r) {
            float s0 = acc0[r] * 0.0625f;
            float s1 = acc1[r] * 0.0625f;
            if (row0 + r == 0) {                 // global query position 0
                s0 = (s0 + cbias[t]) * sh;
                s1 = (s1 + cbias[t + 256]) * sh;
            }
            ps[r][t] = s0;
            ps[r][t + 256] = s1;
        }
    }
    __syncthreads();

    // ---- softmax: wave w handles rows w, w+4, w+8, w+12 ----
    {
        const int wave = t >> 6, lane = t & 63;
#pragma unroll
        for (int rr = 0; rr < 4; ++rr) {
            const int r = wave + rr * 4;
            float vals[8];
            float m = -1e30f;
#pragma unroll
            for (int j = 0; j < 8; ++j) {
                vals[j] = ps[r][lane + j * 64];
                m = fmaxf(m, vals[j]);
            }
#pragma unroll
            for (int off = 32; off; off >>= 1) m = fmaxf(m, __shfl_xor(m, off));
            float sum = 0.0f;
#pragma unroll
            for (int j = 0; j < 8; ++j) { vals[j] = expf(vals[j] - m); sum += vals[j]; }
#pragma unroll
            for (int off = 32; off; off >>= 1) sum += __shfl_xor(sum, off);
            const float inv = 1.0f / sum;
#pragma unroll
            for (int j = 0; j < 8; ++j) ps[r][lane + j * 64] = vals[j] * inv;
        }
    }
    __syncthreads();

    // ---- head-0 probabilities -> d_out attn region [B, L, L] ----
    if (h == 0) {
        float* ob = out_attn + ((size_t)b * 512 + row0) * 512;
#pragma unroll 4
        for (int it = 0; it < 32; ++it) {
            const int flat = t + it * 256;
            const int r = flat >> 9, m = flat & 511;
            ob[(size_t)r * 512 + m] = ps[r][m];
        }
    }

    // ---- PV: thread owns d = t for all 16 rows; emit bf16 hi/lo planes ----
    {
        float accp[16];
#pragma unroll
        for (int r = 0; r < 16; ++r) accp[r] = 0.0f;
        const float* vbp = v + (((size_t)b * 512) * 4 + h) * 256 + t;
        for (int m = 0; m < 512; m += 4) {
            const float v0 = vbp[(size_t)(m + 0) * 1024];
            const float v1 = vbp[(size_t)(m + 1) * 1024];
            const float v2 = vbp[(size_t)(m + 2) * 1024];
            const float v3 = vbp[(size_t)(m + 3) * 1024];
#pragma unroll
            for (int r = 0; r < 16; ++r) {
                const float4 p = *(const float4*)&ps[r][m];
                accp[r] += p.x * v0 + p.y * v1 + p.z * v2 + p.w * v3;
            }
        }
        const size_t ob = (((size_t)b * 512 + row0) * 4 + h) * 256 + t;
#pragma unroll
        for (int r = 0; r < 16; ++r) {
            u16 hh, ll;
            split2(accp[r], hh, ll);
            ao_hi[ob + (size_t)r * 1024] = hh;
            ao_lo[ob + (size_t)r * 1024] = ll;
        }
    }
}

__global__ void copy_kernel(const float* __restrict__ in, float* __restrict__ out, int n) {
    const int i = blockIdx.x * blockDim.x + threadIdx.x;
    if (i < n) out[i] = in[i];
}

// ---------------------------------------------------------------------------
// Orchestration. Workspace = exactly 128 MiB (proven safe in round 2).
// Live ranges (stream-ordered, no overlaps):
//   [0,16)MB   : wq/wk/wv/wo T-planes (hi+lo, 2 MB per plane)
//   [16,32)MB  : w1T planes (hi 8 + lo 8)
//   [32,48)MB  : sln_hi -> ao_hi (after QKV) -> hid_hi (after Wo)
//   [48,64)MB  : sln_lo -> ao_lo             -> hid_lo
//   [64,96)MB  : kbuf fp32 -> w2T planes (hi 8 + lo 8) after attention
//   [96,128)MB : vbuf fp32 -> hbuf planes (hi 16 + lo 16) after attention
//   q fp32 parked in d_out's s-region (dead once Wo overwrites it).
// MLP runs in 4 K-quarters of 1024 so hidden-quarter planes fit in 16 MB each.
// d_out: [ s (8,388,608) | z (4,096) | attn_head0 (4,194,304) ] floats.
// ---------------------------------------------------------------------------
extern "C" void kernel_launch(void* const* d_in, const int* in_sizes, int n_in,
                              void* d_out, int out_size, void* d_ws, size_t ws_size,
                              hipStream_t stream) {
    (void)in_sizes; (void)n_in; (void)out_size; (void)ws_size;

    const float* s     = (const float*)d_in[0];
    const float* z     = (const float*)d_in[1];
    const float* wq    = (const float*)d_in[2];
    const float* bq    = (const float*)d_in[3];
    const float* wk    = (const float*)d_in[4];
    const float* bk    = (const float*)d_in[5];
    const float* wv    = (const float*)d_in[6];
    const float* bv    = (const float*)d_in[7];
    const float* wo    = (const float*)d_in[8];
    const float* bo    = (const float*)d_in[9];
    const float* cbias = (const float*)d_in[10];
    const float* sharp = (const float*)d_in[11];
    const float* ln_g  = (const float*)d_in[12];
    const float* ln_b  = (const float*)d_in[13];
    const float* w1    = (const float*)d_in[14];
    const float* b1    = (const float*)d_in[15];
    const float* w2    = (const float*)d_in[16];
    const float* b2    = (const float*)d_in[17];

    const size_t MB = 1024 * 1024;
    unsigned char* wsb = (unsigned char*)d_ws;

    u16* wqT_h = (u16*)(wsb + 0 * MB);
    u16* wqT_l = (u16*)(wsb + 2 * MB);
    u16* wkT_h = (u16*)(wsb + 4 * MB);
    u16* wkT_l = (u16*)(wsb + 6 * MB);
    u16* wvT_h = (u16*)(wsb + 8 * MB);
    u16* wvT_l = (u16*)(wsb + 10 * MB);
    u16* woT_h = (u16*)(wsb + 12 * MB);
    u16* woT_l = (u16*)(wsb + 14 * MB);
    u16* w1T_h = (u16*)(wsb + 16 * MB);
    u16* w1T_l = (u16*)(wsb + 24 * MB);
    u16* sln_h = (u16*)(wsb + 32 * MB);
    u16* sln_l = (u16*)(wsb + 48 * MB);
    float* kbuf = (float*)(wsb + 64 * MB);
    float* vbuf = (float*)(wsb + 96 * MB);
    // reuses (stream-ordered):
    u16* ao_h  = sln_h;                   // attn-out planes (sln dead after QKV)
    u16* ao_l  = sln_l;
    u16* w2T_h = (u16*)(wsb + 64 * MB);   // after attention (kbuf dead)
    u16* w2T_l = (u16*)(wsb + 72 * MB);
    u16* hid_h = (u16*)(wsb + 32 * MB);   // hidden-quarter planes, 16 MB each
    u16* hid_l = (u16*)(wsb + 48 * MB);   //   (ao planes dead after Wo)
    u16* hb_h  = (u16*)(wsb + 96 * MB);   // LN2 planes (vbuf dead)
    u16* hb_l  = (u16*)(wsb + 112 * MB);

    const size_t U = (size_t)8192 * 1024;
    float* out_s    = (float*)d_out;
    float* out_z    = out_s + U;
    float* out_attn = out_z + 16 * 256;
    float* qbuf     = out_s;              // q parked in d_out s-region

    // 1. Weight prep (wq/wk/wv/wo/w1 now; w2 later into kbuf's space)
    split_t_kernel<<<dim3(16, 16), 256, 0, stream>>>(wq, wqT_h, wqT_l, 1024, 1024);
    split_t_kernel<<<dim3(16, 16), 256, 0, stream>>>(wk, wkT_h, wkT_l, 1024, 1024);
    split_t_kernel<<<dim3(16, 16), 256, 0, stream>>>(wv, wvT_h, wvT_l, 1024, 1024);
    split_t_kernel<<<dim3(16, 16), 256, 0, stream>>>(wo, woT_h, woT_l, 1024, 1024);
    split_t_kernel<<<dim3(64, 16), 256, 0, stream>>>(w1, w1T_h, w1T_l, 1024, 4096);

    // 2. LN1 -> sln planes
    ln_split_kernel<<<8192, 256, 0, stream>>>(s, nullptr, nullptr, sln_h, sln_l);

    // 3. QKV projections (fp32 outputs for the fp32 attention kernel)
    const dim3 gq(8, 64);
    mgemm<false, false, false, false><<<gq, 256, 0, stream>>>(
        sln_h, sln_l, wqT_h, wqT_l, bq, nullptr, qbuf, nullptr, nullptr, 8192, 1024, 1024, 1024);
    mgemm<false, false, false, false><<<gq, 256, 0, stream>>>(
        sln_h, sln_l, wkT_h, wkT_l, bk, nullptr, kbuf, nullptr, nullptr, 8192, 1024, 1024, 1024);
    mgemm<false, false, false, false><<<gq, 256, 0, stream>>>(
        sln_h, sln_l, wvT_h, wvT_l, bv, nullptr, vbuf, nullptr, nullptr, 8192, 1024, 1024, 1024);

    // 4. Attention: ao planes (sln slots), head-0 probs -> d_out
    attn_kernel<<<2048, 256, 0, stream>>>(qbuf, kbuf, vbuf, cbias, sharp, ao_h, ao_l, out_attn);

    // 5. w2 prep into kbuf's dead space
    split_t_kernel<<<dim3(16, 64), 256, 0, stream>>>(w2, w2T_h, w2T_l, 4096, 1024);

    // 6. Output projection + residual: out_s = attn @ wo + bo + s  (overwrites q)
    mgemm<false, true, false, false><<<gq, 256, 0, stream>>>(
        ao_h, ao_l, woT_h, woT_l, bo, s, out_s, nullptr, nullptr, 8192, 1024, 1024, 1024);

    // 7. LN2 -> hbuf planes
    ln_split_kernel<<<8192, 256, 0, stream>>>(out_s, ln_g, ln_b, hb_h, hb_l);

    // 8. MLP in 4 K-quarters of 1024 (hid planes 16 MB each, no overlap):
    //    hid = relu(hbuf @ w1[:, j*1024:...] + b1[...]) -> planes
    //    out_s += hid @ w2[j*1024:(j+1)*1024, :]   (+ b2 on pass 0)
    for (int j = 0; j < 4; ++j) {
        mgemm<true, false, false, true><<<gq, 256, 0, stream>>>(
            hb_h, hb_l, w1T_h + (size_t)j * 1024 * 1024, w1T_l + (size_t)j * 1024 * 1024,
            b1 + (size_t)j * 1024, nullptr, nullptr, hid_h, hid_l, 8192, 1024, 1024, 1024);
        mgemm<false, false, true, false><<<gq, 256, 0, stream>>>(
            hid_h, hid_l, w2T_h + (size_t)j * 1024, w2T_l + (size_t)j * 1024,
            (j == 0) ? b2 : nullptr, nullptr, out_s, nullptr, nullptr, 8192, 1024, 1024, 4096);
    }

    // 9. z passthrough
    copy_kernel<<<16, 256, 0, stream>>>(z, out_z, 4096);
}

// Round 5
// 2708.035 us; speedup vs baseline: 1.1922x; 1.0473x over previous
//
#include <hip/hip_runtime.h>
#include <math.h>

// Problem constants: B=16, L=512, D=1024, H=4, hd=256, BL = B*L = 8192.

typedef unsigned short u16;
typedef __attribute__((ext_vector_type(8))) short bf16x8;
typedef __attribute__((ext_vector_type(4))) float f32x4;

// Split fp32 into bf16 hi + bf16 lo (RNE both). x ~= hi + lo with ~2^-16 rel err.
__device__ inline void split2(float x, u16& h, u16& l) {
    union F { float f; unsigned int u; };
    F a; a.f = x;
    unsigned int hu = (a.u + 0x7FFFu + ((a.u >> 16) & 1u)) & 0xFFFF0000u;
    h = (u16)(hu >> 16);
    F hf; hf.u = hu;
    F r; r.f = x - hf.f;
    l = (u16)((r.u + 0x7FFFu + ((r.u >> 16) & 1u)) >> 16);
}

// ---------------------------------------------------------------------------
// LayerNorm over rows of 1024 floats -> bf16 hi/lo planes (GEMM A operand).
// ---------------------------------------------------------------------------
__global__ __launch_bounds__(256)
void ln_split_kernel(const float* __restrict__ x, const float* __restrict__ g,
                     const float* __restrict__ b, u16* __restrict__ yh,
                     u16* __restrict__ yl) {
    const size_t row = blockIdx.x;
    const float* xr = x + row * 1024;
    const int t = threadIdx.x;

    float4 v = *(const float4*)(xr + t * 4);
    float s  = v.x + v.y + v.z + v.w;
    float ss = v.x * v.x + v.y * v.y + v.z * v.z + v.w * v.w;

#pragma unroll
    for (int off = 32; off; off >>= 1) {
        s  += __shfl_xor(s, off);
        ss += __shfl_xor(ss, off);
    }
    __shared__ float red[8];
    const int wave = t >> 6, lane = t & 63;
    if (lane == 0) { red[wave] = s; red[4 + wave] = ss; }
    __syncthreads();
    s  = red[0] + red[1] + red[2] + red[3];
    ss = red[4] + red[5] + red[6] + red[7];

    const float mu   = s * (1.0f / 1024.0f);
    const float var  = ss * (1.0f / 1024.0f) - mu * mu;
    const float rstd = rsqrtf(var + 1e-5f);

    float o[4] = {(v.x - mu) * rstd, (v.y - mu) * rstd,
                  (v.z - mu) * rstd, (v.w - mu) * rstd};
    if (g != nullptr) {
        float4 gv = *(const float4*)(g + t * 4);
        float4 bv = *(const float4*)(b + t * 4);
        o[0] = o[0] * gv.x + bv.x; o[1] = o[1] * gv.y + bv.y;
        o[2] = o[2] * gv.z + bv.z; o[3] = o[3] * gv.w + bv.w;
    }
    ushort4 vh, vl;
    split2(o[0], vh.x, vl.x); split2(o[1], vh.y, vl.y);
    split2(o[2], vh.z, vl.z); split2(o[3], vh.w, vl.w);
    *(ushort4*)(yh + row * 1024 + t * 4) = vh;
    *(ushort4*)(yl + row * 1024 + t * 4) = vl;
}

// ---------------------------------------------------------------------------
// Weight prep: W[K][N] fp32 -> transposed bf16 planes Thi/Tlo [N][K].
// ---------------------------------------------------------------------------
__global__ __launch_bounds__(256)
void split_t_kernel(const float* __restrict__ W, u16* __restrict__ Thi,
                    u16* __restrict__ Tlo, int K, int N) {
    __shared__ float tile[64][65];
    const int bn = blockIdx.x, bk = blockIdx.y;
    const int t = threadIdx.x;
    const int col = t & 63, rquad = t >> 6;

#pragma unroll
    for (int rep = 0; rep < 16; ++rep) {
        const int row = rep * 4 + rquad;
        tile[row][col] = W[(size_t)(bk * 64 + row) * N + bn * 64 + col];
    }
    __syncthreads();
#pragma unroll
    for (int rep = 0; rep < 16; ++rep) {
        const int n = rep * 4 + rquad;
        const int k = col;
        u16 h, l;
        split2(tile[k][n], h, l);
        const size_t o = (size_t)(bn * 64 + n) * K + bk * 64 + k;
        Thi[o] = h; Tlo[o] = l;
    }
}

// ---------------------------------------------------------------------------
// Split-bf16 MFMA GEMM: C[M,N] = (Ah+Al)[M,K] @ (Bh+Bl)^T[N,K] (+bias)(+R)
// (ReLU)(+=C)(split to Chi/Clo; TRANSV: write planes transposed per-head
// [B*H][hd][L] for the attention PV B-operand).
// Tile 128x128xBK32. 4 waves, each 64x64 = 4x4 frags of 16x16x32.
// ---------------------------------------------------------------------------
template<bool RELU, bool RES, bool ACCUM, bool SPLIT_OUT, bool TRANSV>
__global__ __launch_bounds__(256)
void mgemm(const u16* __restrict__ Ah, const u16* __restrict__ Al,
           const u16* __restrict__ Bh, const u16* __restrict__ Bl,
           const float* __restrict__ bias, const float* __restrict__ R,
           float* __restrict__ C, u16* __restrict__ Chi, u16* __restrict__ Clo,
           int M, int N, int K, int ldb) {
    __shared__ u16 Ahs[128 * 40];
    __shared__ u16 Als[128 * 40];
    __shared__ u16 Bhs[128 * 40];
    __shared__ u16 Bls[128 * 40];

    const int tid  = threadIdx.x;
    const int lane = tid & 63;
    const int wid  = tid >> 6;
    const int wr = wid >> 1, wc = wid & 1;       // wave grid 2x2, 64x64 each
    const int fr = lane & 15, kb = lane >> 4;    // frag row / k-block
    const int row0 = blockIdx.y * 128, col0 = blockIdx.x * 128;

    const int side = tid >> 7;
    const int su = tid & 127;
    const int rq = su >> 2, sb = su & 3;
    const u16* Ph = side ? Bh : Ah;
    const u16* Pl = side ? Bl : Al;
    const int brow = side ? col0 : row0;
    const int pst  = side ? ldb : K;
    u16* Lh = side ? Bhs : Ahs;
    u16* Ll = side ? Bls : Als;

    uint4 sh[4], sl[4];
#pragma unroll
    for (int s2 = 0; s2 < 4; ++s2) {
        const size_t off = (size_t)(brow + s2 * 32 + rq) * pst + sb * 8;
        sh[s2] = *(const uint4*)(Ph + off);
        sl[s2] = *(const uint4*)(Pl + off);
    }
#pragma unroll
    for (int s2 = 0; s2 < 4; ++s2) {
        const int r = s2 * 32 + rq;
        *(uint4*)&Lh[r * 40 + sb * 8] = sh[s2];
        *(uint4*)&Ll[r * 40 + sb * 8] = sl[s2];
    }

    f32x4 acc[4][4];
#pragma unroll
    for (int i = 0; i < 4; ++i)
#pragma unroll
        for (int j = 0; j < 4; ++j)
            acc[i][j] = (f32x4){0.f, 0.f, 0.f, 0.f};

    for (int ks = 0; ks < K; ks += 32) {
        __syncthreads();
        if (ks + 32 < K) {
#pragma unroll
            for (int s2 = 0; s2 < 4; ++s2) {
                const size_t off = (size_t)(brow + s2 * 32 + rq) * pst + (ks + 32) + sb * 8;
                sh[s2] = *(const uint4*)(Ph + off);
                sl[s2] = *(const uint4*)(Pl + off);
            }
        }
        bf16x8 fah[4], fal[4], fbh[4], fbl[4];
#pragma unroll
        for (int i = 0; i < 4; ++i) {
            const int ar = wr * 64 + i * 16 + fr;
            fah[i] = *(const bf16x8*)&Ahs[ar * 40 + kb * 8];
            fal[i] = *(const bf16x8*)&Als[ar * 40 + kb * 8];
            const int br = wc * 64 + i * 16 + fr;
            fbh[i] = *(const bf16x8*)&Bhs[br * 40 + kb * 8];
            fbl[i] = *(const bf16x8*)&Bls[br * 40 + kb * 8];
        }
#pragma unroll
        for (int mi = 0; mi < 4; ++mi)
#pragma unroll
            for (int nj = 0; nj < 4; ++nj) {
                acc[mi][nj] = __builtin_amdgcn_mfma_f32_16x16x32_bf16(fah[mi], fbh[nj], acc[mi][nj], 0, 0, 0);
                acc[mi][nj] = __builtin_amdgcn_mfma_f32_16x16x32_bf16(fah[mi], fbl[nj], acc[mi][nj], 0, 0, 0);
                acc[mi][nj] = __builtin_amdgcn_mfma_f32_16x16x32_bf16(fal[mi], fbh[nj], acc[mi][nj], 0, 0, 0);
            }
        __syncthreads();
        if (ks + 32 < K) {
#pragma unroll
            for (int s2 = 0; s2 < 4; ++s2) {
                const int r = s2 * 32 + rq;
                *(uint4*)&Lh[r * 40 + sb * 8] = sh[s2];
                *(uint4*)&Ll[r * 40 + sb * 8] = sl[s2];
            }
        }
    }

    // Epilogue. C/D frag: col = lane&15, row = (lane>>4)*4 + i.
#pragma unroll
    for (int mi = 0; mi < 4; ++mi)
#pragma unroll
        for (int nj = 0; nj < 4; ++nj) {
            const int gc = col0 + wc * 64 + nj * 16 + fr;
            const float bv = (bias != nullptr) ? bias[gc] : 0.0f;
#pragma unroll
            for (int i = 0; i < 4; ++i) {
                const int gr = row0 + wr * 64 + mi * 16 + kb * 4 + i;
                const size_t o = (size_t)gr * N + gc;
                float v2 = acc[mi][nj][i] + bv;
                if (RES)   v2 += R[o];
                if (RELU)  v2 = fmaxf(v2, 0.0f);
                if (ACCUM) v2 += C[o];
                if (SPLIT_OUT) {
                    u16 hh, ll; split2(v2, hh, ll);
                    size_t ot = o;
                    if (TRANSV) {
                        // [BL][D] -> per-head transposed [B*H][hd][L]
                        const int bb = gr >> 9, lpos = gr & 511;
                        const int hh2 = gc >> 8, dd = gc & 255;
                        ot = (((size_t)bb * 4 + hh2) * 256 + dd) * 512 + lpos;
                    }
                    Chi[ot] = hh; Clo[ot] = ll;
                } else {
                    C[o] = v2;
                }
            }
        }
}

// ---------------------------------------------------------------------------
// MFMA attention. One block = (b, h, 16-q-row tile); 4 waves.
// q/k planes: [BL][1024] bf16 hi/lo (col = h*256+d). vt planes: [B*H][256][512].
// Scores via mfma(Q,K) (A.B^T form, both [row][k]); softmax in LDS; P split
// to bf16 planes in LDS; PV via mfma(P,Vt). K/V frags read direct from
// global (L2-resident, ~1MB/head) -- no K/V LDS staging.
// ---------------------------------------------------------------------------
__global__ __launch_bounds__(256)
void mfma_attn(const u16* __restrict__ qh, const u16* __restrict__ ql,
               const u16* __restrict__ kh, const u16* __restrict__ kl,
               const u16* __restrict__ vth, const u16* __restrict__ vtl,
               const float* __restrict__ cbias, const float* __restrict__ sharp,
               u16* __restrict__ ao_h, u16* __restrict__ ao_l,
               float* __restrict__ out_attn) {
    __shared__ float sc[16 * 520];   // scores, padded (33.3 KB)
    __shared__ u16 ph[16 * 520];     // P hi plane (16.6 KB)
    __shared__ u16 pl[16 * 520];     // P lo plane (16.6 KB)

    const int blk = blockIdx.x;           // 2048 = 16b * 4h * 32qt
    const int b   = blk >> 7;
    const int h   = (blk >> 5) & 3;
    const int qt  = blk & 31;
    const int t   = threadIdx.x;
    const int wid = t >> 6, lane = t & 63;
    const int fr = lane & 15, kg = lane >> 4;

    // ---- Q fragments to registers: rows qt*16 + fr, 8 k-blocks x hi/lo ----
    bf16x8 qfh[8], qfl[8];
    {
        const size_t qoff = ((size_t)b * 512 + qt * 16 + fr) * 1024 + h * 256 + kg * 8;
#pragma unroll
        for (int kb2 = 0; kb2 < 8; ++kb2) {
            qfh[kb2] = *(const bf16x8*)(qh + qoff + kb2 * 32);
            qfl[kb2] = *(const bf16x8*)(ql + qoff + kb2 * 32);
        }
    }

    // ---- scores: wave owns key-cols [wid*128, wid*128+128), 8 col-frags ----
    const float sharp_val = sharp[0];
#pragma unroll
    for (int cf = 0; cf < 8; ++cf) {
        const int col0 = wid * 128 + cf * 16;
        const size_t koff = ((size_t)b * 512 + col0 + fr) * 1024 + h * 256 + kg * 8;
        f32x4 acc = (f32x4){0.f, 0.f, 0.f, 0.f};
#pragma unroll
        for (int kb2 = 0; kb2 < 8; ++kb2) {
            const bf16x8 kf_h = *(const bf16x8*)(kh + koff + kb2 * 32);
            const bf16x8 kf_l = *(const bf16x8*)(kl + koff + kb2 * 32);
            acc = __builtin_amdgcn_mfma_f32_16x16x32_bf16(qfh[kb2], kf_h, acc, 0, 0, 0);
            acc = __builtin_amdgcn_mfma_f32_16x16x32_bf16(qfh[kb2], kf_l, acc, 0, 0, 0);
            acc = __builtin_amdgcn_mfma_f32_16x16x32_bf16(qfl[kb2], kf_h, acc, 0, 0, 0);
        }
        const int col = col0 + fr;        // C-frag: col = lane&15
#pragma unroll
        for (int i = 0; i < 4; ++i) {
            const int row_l = kg * 4 + i; // C-frag: row = (lane>>4)*4 + i
            float sv = acc[i] * 0.0625f;
            if (qt == 0 && row_l == 0)    // global q-row 0
                sv = (sv + cbias[col]) * sharp_val;
            sc[row_l * 520 + col] = sv;
        }
    }
    __syncthreads();

    // ---- softmax: wave w rows w*4..w*4+3; 8 cols/lane; split P to planes ----
#pragma unroll
    for (int rr = 0; rr < 4; ++rr) {
        const int r = wid * 4 + rr;
        float vals[8];
        float m = -1e30f;
#pragma unroll
        for (int j = 0; j < 8; ++j) {
            vals[j] = sc[r * 520 + lane + j * 64];
            m = fmaxf(m, vals[j]);
        }
#pragma unroll
        for (int off = 32; off; off >>= 1) m = fmaxf(m, __shfl_xor(m, off));
        float sum = 0.0f;
#pragma unroll
        for (int j = 0; j < 8; ++j) { vals[j] = expf(vals[j] - m); sum += vals[j]; }
#pragma unroll
        for (int off = 32; off; off >>= 1) sum += __shfl_xor(sum, off);
        const float inv = 1.0f / sum;
        float* oa = (h == 0)
            ? out_attn + ((size_t)b * 512 + qt * 16 + r) * 512 : nullptr;
#pragma unroll
        for (int j = 0; j < 8; ++j) {
            const float p = vals[j] * inv;
            const int c = lane + j * 64;
            if (oa != nullptr) oa[c] = p;
            u16 hh, ll; split2(p, hh, ll);
            ph[r * 520 + c] = hh;
            pl[r * 520 + c] = ll;
        }
    }
    __syncthreads();

    // ---- PV: wave owns d-block [wid*64, wid*64+64), 4 d-frags ----
    {
        f32x4 acc4[4];
#pragma unroll
        for (int f = 0; f < 4; ++f) acc4[f] = (f32x4){0.f, 0.f, 0.f, 0.f};
        const size_t vtbase = (((size_t)b * 4 + h) * 256 + wid * 64 + fr) * 512 + kg * 8;
        for (int kb2 = 0; kb2 < 16; ++kb2) {
            const bf16x8 pfh = *(const bf16x8*)&ph[fr * 520 + kb2 * 32 + kg * 8];
            const bf16x8 pfl = *(const bf16x8*)&pl[fr * 520 + kb2 * 32 + kg * 8];
#pragma unroll
            for (int f = 0; f < 4; ++f) {
                const size_t vo = vtbase + (size_t)f * 16 * 512 + kb2 * 32;
                const bf16x8 vf_h = *(const bf16x8*)(vth + vo);
                const bf16x8 vf_l = *(const bf16x8*)(vtl + vo);
                acc4[f] = __builtin_amdgcn_mfma_f32_16x16x32_bf16(pfh, vf_h, acc4[f], 0, 0, 0);
                acc4[f] = __builtin_amdgcn_mfma_f32_16x16x32_bf16(pfh, vf_l, acc4[f], 0, 0, 0);
                acc4[f] = __builtin_amdgcn_mfma_f32_16x16x32_bf16(pfl, vf_h, acc4[f], 0, 0, 0);
            }
        }
#pragma unroll
        for (int f = 0; f < 4; ++f) {
#pragma unroll
            for (int i = 0; i < 4; ++i) {
                const int row_l = kg * 4 + i;
                const size_t o = ((size_t)b * 512 + qt * 16 + row_l) * 1024
                               + h * 256 + wid * 64 + f * 16 + fr;
                u16 hh, ll; split2(acc4[f][i], hh, ll);
                ao_h[o] = hh; ao_l[o] = ll;
            }
        }
    }
}

__global__ void copy_kernel(const float* __restrict__ in, float* __restrict__ out, int n) {
    const int i = blockIdx.x * blockDim.x + threadIdx.x;
    if (i < n) out[i] = in[i];
}

// ---------------------------------------------------------------------------
// Orchestration. Workspace = 128 MiB (proven safe). Live ranges:
//   [0,16)   : wq/wk/wv/wo T-planes (2 MB each plane)
//   [16,32)  : w1T planes (hi 8 + lo 8)
//   [32,64)  : sln planes -> ao planes (after QKV) -> hid planes (after Wo)
//   [64,96)  : k planes -> w2T planes [64,80) after attention
//   [96,128) : vt planes -> hbuf planes after attention
//   q planes : parked in d_out s-region (32 MB; dead before Wo writes out_s)
// d_out: [ s (8,388,608) | z (4,096) | attn_head0 (4,194,304) ] floats.
// ---------------------------------------------------------------------------
extern "C" void kernel_launch(void* const* d_in, const int* in_sizes, int n_in,
                              void* d_out, int out_size, void* d_ws, size_t ws_size,
                              hipStream_t stream) {
    (void)in_sizes; (void)n_in; (void)out_size; (void)ws_size;

    const float* s     = (const float*)d_in[0];
    const float* z     = (const float*)d_in[1];
    const float* wq    = (const float*)d_in[2];
    const float* bq    = (const float*)d_in[3];
    const float* wk    = (const float*)d_in[4];
    const float* bk    = (const float*)d_in[5];
    const float* wv    = (const float*)d_in[6];
    const float* bv    = (const float*)d_in[7];
    const float* wo    = (const float*)d_in[8];
    const float* bo    = (const float*)d_in[9];
    const float* cbias = (const float*)d_in[10];
    const float* sharp = (const float*)d_in[11];
    const float* ln_g  = (const float*)d_in[12];
    const float* ln_b  = (const float*)d_in[13];
    const float* w1    = (const float*)d_in[14];
    const float* b1    = (const float*)d_in[15];
    const float* w2    = (const float*)d_in[16];
    const float* b2    = (const float*)d_in[17];

    const size_t MB = 1024 * 1024;
    unsigned char* wsb = (unsigned char*)d_ws;

    u16* wqT_h = (u16*)(wsb + 0 * MB);
    u16* wqT_l = (u16*)(wsb + 2 * MB);
    u16* wkT_h = (u16*)(wsb + 4 * MB);
    u16* wkT_l = (u16*)(wsb + 6 * MB);
    u16* wvT_h = (u16*)(wsb + 8 * MB);
    u16* wvT_l = (u16*)(wsb + 10 * MB);
    u16* woT_h = (u16*)(wsb + 12 * MB);
    u16* woT_l = (u16*)(wsb + 14 * MB);
    u16* w1T_h = (u16*)(wsb + 16 * MB);
    u16* w1T_l = (u16*)(wsb + 24 * MB);
    u16* sln_h = (u16*)(wsb + 32 * MB);
    u16* sln_l = (u16*)(wsb + 48 * MB);
    u16* k_h   = (u16*)(wsb + 64 * MB);
    u16* k_l   = (u16*)(wsb + 80 * MB);
    u16* vt_h  = (u16*)(wsb + 96 * MB);
    u16* vt_l  = (u16*)(wsb + 112 * MB);
    // stream-ordered reuses:
    u16* ao_h  = sln_h;                   // attn-out planes (sln dead after QKV)
    u16* ao_l  = sln_l;
    u16* w2T_h = (u16*)(wsb + 64 * MB);   // after attention (k planes dead)
    u16* w2T_l = (u16*)(wsb + 72 * MB);
    u16* hid_h = (u16*)(wsb + 32 * MB);   // hidden-quarter planes (ao dead)
    u16* hid_l = (u16*)(wsb + 48 * MB);
    u16* hb_h  = (u16*)(wsb + 96 * MB);   // LN2 planes (vt dead)
    u16* hb_l  = (u16*)(wsb + 112 * MB);

    const size_t U = (size_t)8192 * 1024;
    float* out_s    = (float*)d_out;
    float* out_z    = out_s + U;
    float* out_attn = out_z + 16 * 256;
    u16* q_h = (u16*)d_out;               // q planes parked in d_out s-region
    u16* q_l = q_h + U;

    // 1. Weight prep (w2 later, into k planes' slot)
    split_t_kernel<<<dim3(16, 16), 256, 0, stream>>>(wq, wqT_h, wqT_l, 1024, 1024);
    split_t_kernel<<<dim3(16, 16), 256, 0, stream>>>(wk, wkT_h, wkT_l, 1024, 1024);
    split_t_kernel<<<dim3(16, 16), 256, 0, stream>>>(wv, wvT_h, wvT_l, 1024, 1024);
    split_t_kernel<<<dim3(16, 16), 256, 0, stream>>>(wo, woT_h, woT_l, 1024, 1024);
    split_t_kernel<<<dim3(64, 16), 256, 0, stream>>>(w1, w1T_h, w1T_l, 1024, 4096);

    // 2. LN1 -> sln planes
    ln_split_kernel<<<8192, 256, 0, stream>>>(s, nullptr, nullptr, sln_h, sln_l);

    // 3. QKV projections -> split planes (V transposed per head)
    const dim3 gq(8, 64);
    mgemm<false, false, false, true, false><<<gq, 256, 0, stream>>>(
        sln_h, sln_l, wqT_h, wqT_l, bq, nullptr, nullptr, q_h, q_l, 8192, 1024, 1024, 1024);
    mgemm<false, false, false, true, false><<<gq, 256, 0, stream>>>(
        sln_h, sln_l, wkT_h, wkT_l, bk, nullptr, nullptr, k_h, k_l, 8192, 1024, 1024, 1024);
    mgemm<false, false, false, true, true><<<gq, 256, 0, stream>>>(
        sln_h, sln_l, wvT_h, wvT_l, bv, nullptr, nullptr, vt_h, vt_l, 8192, 1024, 1024, 1024);

    // 4. Attention: ao planes (over sln), head-0 probs -> d_out
    mfma_attn<<<2048, 256, 0, stream>>>(q_h, q_l, k_h, k_l, vt_h, vt_l,
                                        cbias, sharp, ao_h, ao_l, out_attn);

    // 5. w2 prep into k planes' dead space
    split_t_kernel<<<dim3(16, 64), 256, 0, stream>>>(w2, w2T_h, w2T_l, 4096, 1024);

    // 6. Output projection + residual: out_s = attn @ wo + bo + s (overwrites q)
    mgemm<false, true, false, false, false><<<gq, 256, 0, stream>>>(
        ao_h, ao_l, woT_h, woT_l, bo, s, out_s, nullptr, nullptr, 8192, 1024, 1024, 1024);

    // 7. LN2 -> hbuf planes
    ln_split_kernel<<<8192, 256, 0, stream>>>(out_s, ln_g, ln_b, hb_h, hb_l);

    // 8. MLP in 4 K-quarters of 1024:
    //    hid = relu(hbuf @ w1[:, j*1024:...] + b1) -> planes
    //    out_s += hid @ w2[j*1024:(j+1)*1024, :]   (+ b2 on pass 0)
    for (int j = 0; j < 4; ++j) {
        mgemm<true, false, false, true, false><<<gq, 256, 0, stream>>>(
            hb_h, hb_l, w1T_h + (size_t)j * 1024 * 1024, w1T_l + (size_t)j * 1024 * 1024,
            b1 + (size_t)j * 1024, nullptr, nullptr, hid_h, hid_l, 8192, 1024, 1024, 1024);
        mgemm<false, false, true, false, false><<<gq, 256, 0, stream>>>(
            hid_h, hid_l, w2T_h + (size_t)j * 1024, w2T_l + (size_t)j * 1024,
            (j == 0) ? b2 : nullptr, nullptr, out_s, nullptr, nullptr, 8192, 1024, 1024, 4096);
    }

    // 9. z passthrough
    copy_kernel<<<16, 256, 0, stream>>>(z, out_z, 4096);
}

// Round 6
// 1158.375 us; speedup vs baseline: 2.7872x; 2.3378x over previous
//
#include <hip/hip_runtime.h>
#include <math.h>

// Problem constants: B=16, L=512, D=1024, H=4, hd=256, BL = B*L = 8192.

typedef unsigned short u16;
typedef __attribute__((ext_vector_type(8))) short bf16x8;
typedef __attribute__((ext_vector_type(4))) float f32x4;

// Split fp32 into bf16 hi + bf16 lo (RNE both). x ~= hi + lo with ~2^-16 rel err.
__device__ inline void split2(float x, u16& h, u16& l) {
    union F { float f; unsigned int u; };
    F a; a.f = x;
    unsigned int hu = (a.u + 0x7FFFu + ((a.u >> 16) & 1u)) & 0xFFFF0000u;
    h = (u16)(hu >> 16);
    F hf; hf.u = hu;
    F r; r.f = x - hf.f;
    l = (u16)((r.u + 0x7FFFu + ((r.u >> 16) & 1u)) >> 16);
}

// Async global->LDS, 16 B per lane. LDS dest is wave-uniform base + lane*16.
__device__ inline void gload16(const void* g, void* l) {
    __builtin_amdgcn_global_load_lds(
        (const __attribute__((address_space(1))) void*)g,
        (__attribute__((address_space(3))) void*)l, 16, 0, 0);
}

// ---------------------------------------------------------------------------
// LayerNorm over rows of 1024 floats -> bf16 hi/lo planes (GEMM A operand).
// ---------------------------------------------------------------------------
__global__ __launch_bounds__(256)
void ln_split_kernel(const float* __restrict__ x, const float* __restrict__ g,
                     const float* __restrict__ b, u16* __restrict__ yh,
                     u16* __restrict__ yl) {
    const size_t row = blockIdx.x;
    const float* xr = x + row * 1024;
    const int t = threadIdx.x;

    float4 v = *(const float4*)(xr + t * 4);
    float s  = v.x + v.y + v.z + v.w;
    float ss = v.x * v.x + v.y * v.y + v.z * v.z + v.w * v.w;

#pragma unroll
    for (int off = 32; off; off >>= 1) {
        s  += __shfl_xor(s, off);
        ss += __shfl_xor(ss, off);
    }
    __shared__ float red[8];
    const int wave = t >> 6, lane = t & 63;
    if (lane == 0) { red[wave] = s; red[4 + wave] = ss; }
    __syncthreads();
    s  = red[0] + red[1] + red[2] + red[3];
    ss = red[4] + red[5] + red[6] + red[7];

    const float mu   = s * (1.0f / 1024.0f);
    const float var  = ss * (1.0f / 1024.0f) - mu * mu;
    const float rstd = rsqrtf(var + 1e-5f);

    float o[4] = {(v.x - mu) * rstd, (v.y - mu) * rstd,
                  (v.z - mu) * rstd, (v.w - mu) * rstd};
    if (g != nullptr) {
        float4 gv = *(const float4*)(g + t * 4);
        float4 bv = *(const float4*)(b + t * 4);
        o[0] = o[0] * gv.x + bv.x; o[1] = o[1] * gv.y + bv.y;
        o[2] = o[2] * gv.z + bv.z; o[3] = o[3] * gv.w + bv.w;
    }
    ushort4 vh, vl;
    split2(o[0], vh.x, vl.x); split2(o[1], vh.y, vl.y);
    split2(o[2], vh.z, vl.z); split2(o[3], vh.w, vl.w);
    *(ushort4*)(yh + row * 1024 + t * 4) = vh;
    *(ushort4*)(yl + row * 1024 + t * 4) = vl;
}

// ---------------------------------------------------------------------------
// Weight prep: W[K][N] fp32 -> transposed bf16 planes Thi/Tlo [N][K].
// ---------------------------------------------------------------------------
__global__ __launch_bounds__(256)
void split_t_kernel(const float* __restrict__ W, u16* __restrict__ Thi,
                    u16* __restrict__ Tlo, int K, int N) {
    __shared__ float tile[64][65];
    const int bn = blockIdx.x, bk = blockIdx.y;
    const int t = threadIdx.x;
    const int col = t & 63, rquad = t >> 6;

#pragma unroll
    for (int rep = 0; rep < 16; ++rep) {
        const int row = rep * 4 + rquad;
        tile[row][col] = W[(size_t)(bk * 64 + row) * N + bn * 64 + col];
    }
    __syncthreads();
#pragma unroll
    for (int rep = 0; rep < 16; ++rep) {
        const int n = rep * 4 + rquad;
        const int k = col;
        u16 h, l;
        split2(tile[k][n], h, l);
        const size_t o = (size_t)(bn * 64 + n) * K + bk * 64 + k;
        Thi[o] = h; Tlo[o] = l;
    }
}

// ---------------------------------------------------------------------------
// Split-bf16 MFMA GEMM v2 (m97 structure): C = (Ah+Al) @ (Bh+Bl)^T.
// Tiles [128][32] u16 unpadded, staged via global_load_lds (16B/lane),
// single-buffered; per K-step: barrier / ds_read frags / barrier /
// STAGE(next) overlapped with 48 MFMAs.
// A planes: [M][K] bf16 (lda = K). B planes: [N][K] bf16 (ldb param).
// ---------------------------------------------------------------------------
template<bool RELU, bool RES, bool ACCUM, bool SPLIT_OUT, bool TRANSV>
__global__ __launch_bounds__(256)
void mgemm(const u16* __restrict__ Ah, const u16* __restrict__ Al,
           const u16* __restrict__ Bh, const u16* __restrict__ Bl,
           const float* __restrict__ bias, const float* __restrict__ R,
           float* __restrict__ C, u16* __restrict__ Chi, u16* __restrict__ Clo,
           int M, int N, int K, int ldb) {
    __shared__ u16 Ahs[128 * 32];
    __shared__ u16 Als[128 * 32];
    __shared__ u16 Bhs[128 * 32];
    __shared__ u16 Bls[128 * 32];

    const int tid  = threadIdx.x;
    const int lane = tid & 63;
    const int wid  = tid >> 6;
    const int wr = wid >> 1, wc = wid & 1;       // wave grid 2x2, 64x64 each
    const int fr = lane & 15, kb = lane >> 4;    // frag row / k-block
    const int row0 = blockIdx.y * 128, col0 = blockIdx.x * 128;

    // Staging geometry: issue j of a tile covers LDS bytes [j*4096 + wid*1024
    // + lane*16] == row (j*64 + wid*16 + lane/4), u16-col (lane%4)*8.
    const int srow   = wid * 16 + (lane >> 2);   // 0..63
    const int scol   = (lane & 3) * 8;
    const int ldsoff = wid * 512;                // u16 per-wave offset in 4KB block

#define ST_TILE(LDS, P, BR, PST, KS)                                          \
    gload16(P + (size_t)((BR) + srow) * (PST) + (KS) + scol, LDS + ldsoff);   \
    gload16(P + (size_t)((BR) + 64 + srow) * (PST) + (KS) + scol,             \
            LDS + 2048 + ldsoff);

#define STAGE(KS)                                                             \
    ST_TILE(Ahs, Ah, row0, K, KS)                                             \
    ST_TILE(Als, Al, row0, K, KS)                                             \
    ST_TILE(Bhs, Bh, col0, ldb, KS)                                           \
    ST_TILE(Bls, Bl, col0, ldb, KS)

    f32x4 acc[4][4];
#pragma unroll
    for (int i = 0; i < 4; ++i)
#pragma unroll
        for (int j = 0; j < 4; ++j)
            acc[i][j] = (f32x4){0.f, 0.f, 0.f, 0.f};

    STAGE(0)

    for (int ks = 0; ks < K; ks += 32) {
        __syncthreads();   // drains gload vmcnt -> tile visible to all waves

        bf16x8 fah[4], fal[4], fbh[4], fbl[4];
#pragma unroll
        for (int i = 0; i < 4; ++i) {
            const int ar = (wr * 64 + i * 16 + fr) * 32 + kb * 8;
            fah[i] = *(const bf16x8*)&Ahs[ar];
            fal[i] = *(const bf16x8*)&Als[ar];
            const int br = (wc * 64 + i * 16 + fr) * 32 + kb * 8;
            fbh[i] = *(const bf16x8*)&Bhs[br];
            fbl[i] = *(const bf16x8*)&Bls[br];
        }
        __syncthreads();   // all waves' ds_reads retired -> safe to overwrite

        if (ks + 32 < K) { STAGE(ks + 32) }   // overlaps with MFMA below

#pragma unroll
        for (int mi = 0; mi < 4; ++mi)
#pragma unroll
            for (int nj = 0; nj < 4; ++nj) {
                acc[mi][nj] = __builtin_amdgcn_mfma_f32_16x16x32_bf16(fah[mi], fbh[nj], acc[mi][nj], 0, 0, 0);
                acc[mi][nj] = __builtin_amdgcn_mfma_f32_16x16x32_bf16(fah[mi], fbl[nj], acc[mi][nj], 0, 0, 0);
                acc[mi][nj] = __builtin_amdgcn_mfma_f32_16x16x32_bf16(fal[mi], fbh[nj], acc[mi][nj], 0, 0, 0);
            }
    }
#undef STAGE
#undef ST_TILE

    // Epilogue. C/D frag: col = lane&15, row = (lane>>4)*4 + i.
#pragma unroll
    for (int mi = 0; mi < 4; ++mi)
#pragma unroll
        for (int nj = 0; nj < 4; ++nj) {
            const int gc = col0 + wc * 64 + nj * 16 + fr;
            const float bv = (bias != nullptr) ? bias[gc] : 0.0f;
#pragma unroll
            for (int i = 0; i < 4; ++i) {
                const int gr = row0 + wr * 64 + mi * 16 + kb * 4 + i;
                const size_t o = (size_t)gr * N + gc;
                float v2 = acc[mi][nj][i] + bv;
                if (RES)   v2 += R[o];
                if (RELU)  v2 = fmaxf(v2, 0.0f);
                if (ACCUM) v2 += C[o];
                if (SPLIT_OUT) {
                    u16 hh, ll; split2(v2, hh, ll);
                    size_t ot = o;
                    if (TRANSV) {
                        // [BL][D] -> per-head transposed [B*H][hd][L]
                        const int bb = gr >> 9, lpos = gr & 511;
                        const int hh2 = gc >> 8, dd = gc & 255;
                        ot = (((size_t)bb * 4 + hh2) * 256 + dd) * 512 + lpos;
                    }
                    Chi[ot] = hh; Clo[ot] = ll;
                } else {
                    C[o] = v2;
                }
            }
        }
}

// ---------------------------------------------------------------------------
// MFMA attention. One block = (b, h, 16-q-row tile); 4 waves.
// q/k planes: [BL][1024] bf16 hi/lo (col = h*256+d). vt planes: [B*H][256][512].
// Scores in LDS; P hi/lo planes OVERLAY the dead score rows (row r's 2080 B
// hold ph[r][520] then pl[r][520]) -> LDS 33.3 KB -> 4 blocks/CU.
// ---------------------------------------------------------------------------
__global__ __launch_bounds__(256)
void mfma_attn(const u16* __restrict__ qh, const u16* __restrict__ ql,
               const u16* __restrict__ kh, const u16* __restrict__ kl,
               const u16* __restrict__ vth, const u16* __restrict__ vtl,
               const float* __restrict__ cbias, const float* __restrict__ sharp,
               u16* __restrict__ ao_h, u16* __restrict__ ao_l,
               float* __restrict__ out_attn) {
    __shared__ float sc[16 * 520];   // 33.3 KB; P planes overlay after softmax
    u16* scU = (u16*)sc;             // row r: ph at [r*1040 + c], pl at [+520]

    const int blk = blockIdx.x;           // 2048 = 16b * 4h * 32qt
    const int b   = blk >> 7;
    const int h   = (blk >> 5) & 3;
    const int qt  = blk & 31;
    const int t   = threadIdx.x;
    const int wid = t >> 6, lane = t & 63;
    const int fr = lane & 15, kg = lane >> 4;

    // ---- Q fragments to registers: rows qt*16 + fr, 8 k-blocks x hi/lo ----
    bf16x8 qfh[8], qfl[8];
    {
        const size_t qoff = ((size_t)b * 512 + qt * 16 + fr) * 1024 + h * 256 + kg * 8;
#pragma unroll
        for (int kb2 = 0; kb2 < 8; ++kb2) {
            qfh[kb2] = *(const bf16x8*)(qh + qoff + kb2 * 32);
            qfl[kb2] = *(const bf16x8*)(ql + qoff + kb2 * 32);
        }
    }

    // ---- scores: wave owns key-cols [wid*128, wid*128+128), 8 col-frags ----
    const float sharp_val = sharp[0];
#pragma unroll
    for (int cf = 0; cf < 8; ++cf) {
        const int col0 = wid * 128 + cf * 16;
        const size_t koff = ((size_t)b * 512 + col0 + fr) * 1024 + h * 256 + kg * 8;
        f32x4 acc = (f32x4){0.f, 0.f, 0.f, 0.f};
#pragma unroll
        for (int kb2 = 0; kb2 < 8; ++kb2) {
            const bf16x8 kf_h = *(const bf16x8*)(kh + koff + kb2 * 32);
            const bf16x8 kf_l = *(const bf16x8*)(kl + koff + kb2 * 32);
            acc = __builtin_amdgcn_mfma_f32_16x16x32_bf16(qfh[kb2], kf_h, acc, 0, 0, 0);
            acc = __builtin_amdgcn_mfma_f32_16x16x32_bf16(qfh[kb2], kf_l, acc, 0, 0, 0);
            acc = __builtin_amdgcn_mfma_f32_16x16x32_bf16(qfl[kb2], kf_h, acc, 0, 0, 0);
        }
        const int col = col0 + fr;        // C-frag: col = lane&15
#pragma unroll
        for (int i = 0; i < 4; ++i) {
            const int row_l = kg * 4 + i; // C-frag: row = (lane>>4)*4 + i
            float sv = acc[i] * 0.0625f;
            if (qt == 0 && row_l == 0)    // global q-row 0
                sv = (sv + cbias[col]) * sharp_val;
            sc[row_l * 520 + col] = sv;
        }
    }
    __syncthreads();

    // ---- softmax: wave w rows w*4..w*4+3; split P into overlay planes ----
#pragma unroll
    for (int rr = 0; rr < 4; ++rr) {
        const int r = wid * 4 + rr;
        float vals[8];
        float m = -1e30f;
#pragma unroll
        for (int j = 0; j < 8; ++j) {
            vals[j] = sc[r * 520 + lane + j * 64];
            m = fmaxf(m, vals[j]);
        }
#pragma unroll
        for (int off = 32; off; off >>= 1) m = fmaxf(m, __shfl_xor(m, off));
        float sum = 0.0f;
#pragma unroll
        for (int j = 0; j < 8; ++j) { vals[j] = expf(vals[j] - m); sum += vals[j]; }
#pragma unroll
        for (int off = 32; off; off >>= 1) sum += __shfl_xor(sum, off);
        const float inv = 1.0f / sum;
        float* oa = (h == 0)
            ? out_attn + ((size_t)b * 512 + qt * 16 + r) * 512 : nullptr;
#pragma unroll
        for (int j = 0; j < 8; ++j) {
            const float p = vals[j] * inv;
            const int c = lane + j * 64;
            if (oa != nullptr) oa[c] = p;
            u16 hh, ll; split2(p, hh, ll);
            scU[r * 1040 + c] = hh;          // overlays row r (already in regs)
            scU[r * 1040 + 520 + c] = ll;
        }
    }
    __syncthreads();

    // ---- PV: wave owns d-block [wid*64, wid*64+64), 4 d-frags ----
    {
        f32x4 acc4[4];
#pragma unroll
        for (int f = 0; f < 4; ++f) acc4[f] = (f32x4){0.f, 0.f, 0.f, 0.f};
        const size_t vtbase = (((size_t)b * 4 + h) * 256 + wid * 64 + fr) * 512 + kg * 8;
        for (int kb2 = 0; kb2 < 16; ++kb2) {
            const bf16x8 pfh = *(const bf16x8*)&scU[fr * 1040 + kb2 * 32 + kg * 8];
            const bf16x8 pfl = *(const bf16x8*)&scU[fr * 1040 + 520 + kb2 * 32 + kg * 8];
#pragma unroll
            for (int f = 0; f < 4; ++f) {
                const size_t vo = vtbase + (size_t)f * 16 * 512 + kb2 * 32;
                const bf16x8 vf_h = *(const bf16x8*)(vth + vo);
                const bf16x8 vf_l = *(const bf16x8*)(vtl + vo);
                acc4[f] = __builtin_amdgcn_mfma_f32_16x16x32_bf16(pfh, vf_h, acc4[f], 0, 0, 0);
                acc4[f] = __builtin_amdgcn_mfma_f32_16x16x32_bf16(pfh, vf_l, acc4[f], 0, 0, 0);
                acc4[f] = __builtin_amdgcn_mfma_f32_16x16x32_bf16(pfl, vf_h, acc4[f], 0, 0, 0);
            }
        }
#pragma unroll
        for (int f = 0; f < 4; ++f) {
#pragma unroll
            for (int i = 0; i < 4; ++i) {
                const int row_l = kg * 4 + i;
                const size_t o = ((size_t)b * 512 + qt * 16 + row_l) * 1024
                               + h * 256 + wid * 64 + f * 16 + fr;
                u16 hh, ll; split2(acc4[f][i], hh, ll);
                ao_h[o] = hh; ao_l[o] = ll;
            }
        }
    }
}

__global__ void copy_kernel(const float* __restrict__ in, float* __restrict__ out, int n) {
    const int i = blockIdx.x * blockDim.x + threadIdx.x;
    if (i < n) out[i] = in[i];
}

// ---------------------------------------------------------------------------
// Orchestration. Workspace = 128 MiB (proven safe). Live ranges:
//   [0,16)   : wq/wk/wv/wo T-planes (2 MB each plane)
//   [16,32)  : w1T planes (hi 8 + lo 8)
//   [32,64)  : sln planes -> ao planes (after QKV) -> hid planes (after Wo)
//   [64,96)  : k planes -> w2T planes [64,80) after attention
//   [96,128) : vt planes -> hbuf planes after attention
//   q planes : parked in d_out s-region (32 MB; dead before Wo writes out_s)
// d_out: [ s (8,388,608) | z (4,096) | attn_head0 (4,194,304) ] floats.
// ---------------------------------------------------------------------------
extern "C" void kernel_launch(void* const* d_in, const int* in_sizes, int n_in,
                              void* d_out, int out_size, void* d_ws, size_t ws_size,
                              hipStream_t stream) {
    (void)in_sizes; (void)n_in; (void)out_size; (void)ws_size;

    const float* s     = (const float*)d_in[0];
    const float* z     = (const float*)d_in[1];
    const float* wq    = (const float*)d_in[2];
    const float* bq    = (const float*)d_in[3];
    const float* wk    = (const float*)d_in[4];
    const float* bk    = (const float*)d_in[5];
    const float* wv    = (const float*)d_in[6];
    const float* bv    = (const float*)d_in[7];
    const float* wo    = (const float*)d_in[8];
    const float* bo    = (const float*)d_in[9];
    const float* cbias = (const float*)d_in[10];
    const float* sharp = (const float*)d_in[11];
    const float* ln_g  = (const float*)d_in[12];
    const float* ln_b  = (const float*)d_in[13];
    const float* w1    = (const float*)d_in[14];
    const float* b1    = (const float*)d_in[15];
    const float* w2    = (const float*)d_in[16];
    const float* b2    = (const float*)d_in[17];

    const size_t MB = 1024 * 1024;
    unsigned char* wsb = (unsigned char*)d_ws;

    u16* wqT_h = (u16*)(wsb + 0 * MB);
    u16* wqT_l = (u16*)(wsb + 2 * MB);
    u16* wkT_h = (u16*)(wsb + 4 * MB);
    u16* wkT_l = (u16*)(wsb + 6 * MB);
    u16* wvT_h = (u16*)(wsb + 8 * MB);
    u16* wvT_l = (u16*)(wsb + 10 * MB);
    u16* woT_h = (u16*)(wsb + 12 * MB);
    u16* woT_l = (u16*)(wsb + 14 * MB);
    u16* w1T_h = (u16*)(wsb + 16 * MB);
    u16* w1T_l = (u16*)(wsb + 24 * MB);
    u16* sln_h = (u16*)(wsb + 32 * MB);
    u16* sln_l = (u16*)(wsb + 48 * MB);
    u16* k_h   = (u16*)(wsb + 64 * MB);
    u16* k_l   = (u16*)(wsb + 80 * MB);
    u16* vt_h  = (u16*)(wsb + 96 * MB);
    u16* vt_l  = (u16*)(wsb + 112 * MB);
    // stream-ordered reuses:
    u16* ao_h  = sln_h;                   // attn-out planes (sln dead after QKV)
    u16* ao_l  = sln_l;
    u16* w2T_h = (u16*)(wsb + 64 * MB);   // after attention (k planes dead)
    u16* w2T_l = (u16*)(wsb + 72 * MB);
    u16* hid_h = (u16*)(wsb + 32 * MB);   // hidden-quarter planes (ao dead)
    u16* hid_l = (u16*)(wsb + 48 * MB);
    u16* hb_h  = (u16*)(wsb + 96 * MB);   // LN2 planes (vt dead)
    u16* hb_l  = (u16*)(wsb + 112 * MB);

    const size_t U = (size_t)8192 * 1024;
    float* out_s    = (float*)d_out;
    float* out_z    = out_s + U;
    float* out_attn = out_z + 16 * 256;
    u16* q_h = (u16*)d_out;               // q planes parked in d_out s-region
    u16* q_l = q_h + U;

    // 1. Weight prep (w2 later, into k planes' slot)
    split_t_kernel<<<dim3(16, 16), 256, 0, stream>>>(wq, wqT_h, wqT_l, 1024, 1024);
    split_t_kernel<<<dim3(16, 16), 256, 0, stream>>>(wk, wkT_h, wkT_l, 1024, 1024);
    split_t_kernel<<<dim3(16, 16), 256, 0, stream>>>(wv, wvT_h, wvT_l, 1024, 1024);
    split_t_kernel<<<dim3(16, 16), 256, 0, stream>>>(wo, woT_h, woT_l, 1024, 1024);
    split_t_kernel<<<dim3(64, 16), 256, 0, stream>>>(w1, w1T_h, w1T_l, 1024, 4096);

    // 2. LN1 -> sln planes
    ln_split_kernel<<<8192, 256, 0, stream>>>(s, nullptr, nullptr, sln_h, sln_l);

    // 3. QKV projections -> split planes (V transposed per head)
    const dim3 gq(8, 64);
    mgemm<false, false, false, true, false><<<gq, 256, 0, stream>>>(
        sln_h, sln_l, wqT_h, wqT_l, bq, nullptr, nullptr, q_h, q_l, 8192, 1024, 1024, 1024);
    mgemm<false, false, false, true, false><<<gq, 256, 0, stream>>>(
        sln_h, sln_l, wkT_h, wkT_l, bk, nullptr, nullptr, k_h, k_l, 8192, 1024, 1024, 1024);
    mgemm<false, false, false, true, true><<<gq, 256, 0, stream>>>(
        sln_h, sln_l, wvT_h, wvT_l, bv, nullptr, nullptr, vt_h, vt_l, 8192, 1024, 1024, 1024);

    // 4. Attention: ao planes (over sln), head-0 probs -> d_out
    mfma_attn<<<2048, 256, 0, stream>>>(q_h, q_l, k_h, k_l, vt_h, vt_l,
                                        cbias, sharp, ao_h, ao_l, out_attn);

    // 5. w2 prep into k planes' dead space
    split_t_kernel<<<dim3(16, 64), 256, 0, stream>>>(w2, w2T_h, w2T_l, 4096, 1024);

    // 6. Output projection + residual: out_s = attn @ wo + bo + s (overwrites q)
    mgemm<false, true, false, false, false><<<gq, 256, 0, stream>>>(
        ao_h, ao_l, woT_h, woT_l, bo, s, out_s, nullptr, nullptr, 8192, 1024, 1024, 1024);

    // 7. LN2 -> hbuf planes
    ln_split_kernel<<<8192, 256, 0, stream>>>(out_s, ln_g, ln_b, hb_h, hb_l);

    // 8. MLP in 4 K-quarters of 1024:
    //    hid = relu(hbuf @ w1[:, j*1024:...] + b1) -> planes
    //    out_s += hid @ w2[j*1024:(j+1)*1024, :]   (+ b2 on pass 0)
    for (int j = 0; j < 4; ++j) {
        mgemm<true, false, false, true, false><<<gq, 256, 0, stream>>>(
            hb_h, hb_l, w1T_h + (size_t)j * 1024 * 1024, w1T_l + (size_t)j * 1024 * 1024,
            b1 + (size_t)j * 1024, nullptr, nullptr, hid_h, hid_l, 8192, 1024, 1024, 1024);
        mgemm<false, false, true, false, false><<<gq, 256, 0, stream>>>(
            hid_h, hid_l, w2T_h + (size_t)j * 1024, w2T_l + (size_t)j * 1024,
            (j == 0) ? b2 : nullptr, nullptr, out_s, nullptr, nullptr, 8192, 1024, 1024, 4096);
    }

    // 9. z passthrough
    copy_kernel<<<16, 256, 0, stream>>>(z, out_z, 4096);
}